// Round 5
// baseline (124.338 us; speedup 1.0000x reference)
//
#include <hip/hip_runtime.h>
#include <hip/hip_bf16.h>
#include <cmath>
#include <complex>
#include <algorithm>

// ======================================================================
// Host-side exact port of the reference e3nn wigner_3j (unit Frobenius
// norm, real basis, (-1j)^l phase). Computed once, passed by value.
// ======================================================================

typedef std::complex<double> cd;

static double factd(int n) { double r = 1; for (int i = 2; i <= n; ++i) r *= i; return r; }

static double su2_cg(int j1, int m1, int j2, int m2, int j3, int m3) {
    if (m3 != m1 + m2) return 0.0;
    int vmin = std::max(std::max(-j1 + j2 + m3, -j1 + m1), 0);
    int vmax = std::min(std::min(j2 + j3 + m1, j3 - j1 + j2), j3 + m3);
    double C = std::sqrt((2.0 * j3 + 1.0) *
        (factd(j3 + j1 - j2) * factd(j3 - j1 + j2) * factd(j1 + j2 - j3) *
         factd(j3 + m3) * factd(j3 - m3)) /
        (factd(j1 + j2 + j3 + 1) * factd(j1 - m1) * factd(j1 + m1) *
         factd(j2 - m2) * factd(j2 + m2)));
    double S = 0.0;
    for (int v = vmin; v <= vmax; ++v) {
        double sgn = ((v + j2 + m2) & 1) ? -1.0 : 1.0;
        S += sgn * (factd(j2 + j3 + m1 - v) * factd(j1 - m1 + v)) /
             (factd(v) * factd(j3 - j1 + j2 - v) * factd(j3 + m3 - v) *
              factd(v + j1 - j2 - m3));
    }
    return C * S;
}

static void qmat(int l, cd* q) {
    int n = 2 * l + 1;
    for (int i = 0; i < n * n; ++i) q[i] = cd(0, 0);
    const double s = 1.0 / std::sqrt(2.0);
    for (int m = -l; m < 0; ++m) {
        q[(l + m) * n + (l - m)] = cd(s, 0);
        q[(l + m) * n + (l + m)] = cd(0, -s);
    }
    q[l * n + l] = cd(1, 0);
    for (int m = 1; m <= l; ++m) {
        double sg = (m & 1) ? -1.0 : 1.0;
        q[(l + m) * n + (l + m)] = cd(sg * s, 0);
        q[(l + m) * n + (l - m)] = cd(0, sg * s);
    }
    cd ph(1, 0);
    for (int t = 0; t < l; ++t) ph *= cd(0, -1);
    for (int i = 0; i < n * n; ++i) q[i] *= ph;
}

static void wigner3j_dense(int l1, int l2, int l3, double* outp) {
    int n1 = 2 * l1 + 1, n2 = 2 * l2 + 1, n3 = 2 * l3 + 1;
    double cg[125];
    for (int i = 0; i < n1 * n2 * n3; ++i) cg[i] = 0.0;
    for (int m1 = -l1; m1 <= l1; ++m1)
        for (int m2 = -l2; m2 <= l2; ++m2) {
            int m3 = m1 + m2;
            if (std::abs(m3) <= l3)
                cg[((l1 + m1) * n2 + (l2 + m2)) * n3 + (l3 + m3)] =
                    su2_cg(l1, m1, l2, m2, l3, m3);
        }
    cd q1[25], q2[25], q3[25];
    qmat(l1, q1); qmat(l2, q2); qmat(l3, q3);
    double norm2 = 0.0;
    for (int j = 0; j < n1; ++j)
        for (int l = 0; l < n2; ++l)
            for (int m = 0; m < n3; ++m) {
                cd sum(0, 0);
                for (int i = 0; i < n1; ++i)
                    for (int k = 0; k < n2; ++k)
                        for (int n = 0; n < n3; ++n) {
                            double g = cg[(i * n2 + k) * n3 + n];
                            if (g != 0.0)
                                sum += q1[i * n1 + j] * q2[k * n2 + l] *
                                       std::conj(q3[n * n3 + m]) * g;
                        }
                outp[(j * n2 + l) * n3 + m] = sum.real();
                norm2 += sum.real() * sum.real();
            }
    double inv = 1.0 / std::sqrt(norm2);
    for (int t = 0; t < n1 * n2 * n3; ++t) outp[t] *= inv;
}

// ======================================================================
// Sparsity pattern of the real-basis w3j (structural nonzeros).
// ======================================================================

struct E3 { unsigned char i, j, k; };

constexpr E3 PAT_P0[1]  = {{0,0,0}};
constexpr E3 PAT_P1[3]  = {{0,0,0},{1,1,0},{2,2,0}};
constexpr E3 PAT_P2[5]  = {{0,0,0},{1,1,0},{2,2,0},{3,3,0},{4,4,0}};
constexpr E3 PAT_P3[3]  = {{0,0,0},{0,1,1},{0,2,2}};
constexpr E3 PAT_P4[3]  = {{0,0,0},{1,0,1},{2,0,2}};
constexpr E3 PAT_P5[11] = {{1,2,1},{1,3,2},{1,1,0},{2,2,2},{0,2,0},{2,3,1},
                           {0,1,1},{2,4,2},{0,0,2},{2,0,0},{0,4,0}};
constexpr E3 PAT_P6[11] = {{2,1,1},{2,2,2},{2,0,0},{3,1,2},{1,1,0},{3,2,1},
                           {1,0,1},{4,2,2},{0,0,2},{4,0,0},{0,2,0}};
constexpr E3 PAT_P7[5]  = {{0,0,0},{0,1,1},{0,2,2},{0,3,3},{0,4,4}};
constexpr E3 PAT_P8[11] = {{1,1,2},{1,2,3},{1,0,1},{2,1,3},{0,1,1},{2,2,2},
                           {0,0,2},{2,2,4},{0,0,4},{2,0,0},{0,2,0}};
constexpr E3 PAT_P9[5]  = {{0,0,0},{1,0,1},{2,0,2},{3,0,3},{4,0,4}};
constexpr E3 PAT_P10[25]= {{2,2,2},{2,3,3},{2,1,1},{2,4,4},{2,0,0},{3,2,3},
                           {1,2,1},{3,3,2},{1,1,2},{3,3,4},{1,1,4},{3,1,0},
                           {1,3,0},{3,4,3},{1,0,3},{3,0,1},{1,4,1},{4,2,4},
                           {0,2,0},{4,3,3},{0,1,3},{4,1,1},{0,3,1},{4,4,2},
                           {0,0,2}};

constexpr int OFF_P[11] = {0, 1, 4, 9, 12, 15, 26, 37, 42, 53, 58};

struct W3JArg { float c[83]; };

static W3JArg build_w3j_sparse() {
    struct PD { const E3* pat; int ne; int l1, l2, lo; double alpha; };
    const double a0 = std::sqrt(1.0/3072.0), a1 = std::sqrt(3.0/4096.0),
                 a2 = std::sqrt(5.0/4096.0);
    const PD pd[11] = {
        {PAT_P0, 1, 0,0,0, a0}, {PAT_P1, 3, 1,1,0, a0}, {PAT_P2, 5, 2,2,0, a0},
        {PAT_P3, 3, 0,1,1, a1}, {PAT_P4, 3, 1,0,1, a1}, {PAT_P5,11, 1,2,1, a1},
        {PAT_P6,11, 2,1,1, a1}, {PAT_P7, 5, 0,2,2, a2}, {PAT_P8,11, 1,1,2, a2},
        {PAT_P9, 5, 2,0,2, a2}, {PAT_P10,25,2,2,2, a2}
    };
    W3JArg arg;
    for (int p = 0; p < 11; ++p) {
        double dense[125];
        wigner3j_dense(pd[p].l1, pd[p].l2, pd[p].lo, dense);
        int n2 = 2*pd[p].l2+1, n3 = 2*pd[p].lo+1;
        for (int e = 0; e < pd[p].ne; ++e) {
            const E3& t = pd[p].pat[e];
            arg.c[OFF_P[p] + e] =
                (float)(dense[(t.i * n2 + t.j) * n3 + t.k] * pd[p].alpha);
        }
    }
    return arg;
}

// ======================================================================
// Device
// ======================================================================

typedef __attribute__((ext_vector_type(8))) short short8;
typedef __attribute__((ext_vector_type(4))) float f32x4;

__device__ __forceinline__ unsigned short f2bf_bits(float f) {
    __hip_bfloat16 h = __float2bfloat16(f);
    unsigned short u; __builtin_memcpy(&u, &h, 2); return u;
}

__device__ __forceinline__ unsigned pack2(float lo, float hi) {
    float2 f2; f2.x = lo; f2.y = hi;
    __hip_bfloat162 pk = __float22bfloat162_rn(f2);
    unsigned u; __builtin_memcpy(&u, &pk, 4); return u;
}

// One path: ca_e = c_e*a[i_e] once, then t0/t1 FMAs; pack + LDS store.
template<int NE, int A1, int A2, int D3, int SBASE, int SSTR>
__device__ __forceinline__ void do_path(const E3 (&pat)[NE],
                                        const float* __restrict__ cs,
                                        const float* a, const float* b0,
                                        const float* b1,
                                        unsigned* __restrict__ dst) {
    float ca[NE];
    #pragma unroll
    for (int e = 0; e < NE; ++e) ca[e] = cs[e] * a[A1 + pat[e].i];
    float t0[D3], t1[D3];
    #pragma unroll
    for (int k = 0; k < D3; ++k) { t0[k] = 0.0f; t1[k] = 0.0f; }
    #pragma unroll
    for (int e = 0; e < NE; ++e) {
        const int k = pat[e].k;
        t0[k] = fmaf(ca[e], b0[A2 + pat[e].j], t0[k]);
        t1[k] = fmaf(ca[e], b1[A2 + pat[e].j], t1[k]);
    }
    #pragma unroll
    for (int k = 0; k < D3; ++k)
        dst[(SBASE + k * SSTR) * 256] = pack2(t0[k], t1[k]);
}

__device__ __forceinline__ void build_all(const float* __restrict__ cs,
                                          const float* a, const float* b0,
                                          const float* b1,
                                          unsigned* __restrict__ dst) {
    do_path< 1,0,0,1, 0,1>(PAT_P0,  cs +  0, a, b0, b1, dst);
    do_path< 3,1,1,1, 1,1>(PAT_P1,  cs +  1, a, b0, b1, dst);
    do_path< 5,4,4,1, 2,1>(PAT_P2,  cs +  4, a, b0, b1, dst);
    do_path< 3,0,1,3, 3,4>(PAT_P3,  cs +  9, a, b0, b1, dst);
    do_path< 3,1,0,3, 4,4>(PAT_P4,  cs + 12, a, b0, b1, dst);
    do_path<11,1,4,3, 5,4>(PAT_P5,  cs + 15, a, b0, b1, dst);
    do_path<11,4,1,3, 6,4>(PAT_P6,  cs + 26, a, b0, b1, dst);
    do_path< 5,0,4,5,15,4>(PAT_P7,  cs + 37, a, b0, b1, dst);
    do_path<11,1,1,5,16,4>(PAT_P8,  cs + 42, a, b0, b1, dst);
    do_path< 5,4,0,5,17,4>(PAT_P9,  cs + 53, a, b0, b1, dst);
    do_path<25,4,4,5,18,4>(PAT_P10, cs + 58, a, b0, b1, dst);
}

__device__ __forceinline__ void load_a(const float* __restrict__ x1r, int u,
                                       float* a) {
    a[0] = x1r[u];
    #pragma unroll
    for (int i = 0; i < 3; ++i) a[1 + i] = x1r[32 + u * 3 + i];
    #pragma unroll
    for (int i = 0; i < 5; ++i) a[4 + i] = x1r[128 + u * 5 + i];
}

// B fragment: wsT[p][u][w][v] bf16; lane: n = l&15 -> w, k = (l>>4)*8+j -> v
template<bool USE_WST>
__device__ __forceinline__ short8 load_bfrag(const float* __restrict__ ws,
                                             const unsigned short* __restrict__ wsT,
                                             int p, int u, int w, int vbase) {
    if constexpr (USE_WST) {
        return *(const short8*)(wsT + (((size_t)(p*32+u)*32 + w)*32 + vbase));
    } else {
        short8 r;
        #pragma unroll
        for (int j = 0; j < 8; ++j) {
            float f = ws[((size_t)(p*32+u)*32 + (vbase+j))*32 + w];
            r[j] = (short)f2bf_bits(f);
        }
        return r;
    }
}

// ws prep: wsT[p][u][w][v] bf16 <- ws[p][u][v][w] fp32, plus zero `out`
__global__ void ws_prep(const float* __restrict__ ws,
                        unsigned short* __restrict__ wsT,
                        float* __restrict__ out) {
    __shared__ float tile[32][33];
    const int pu = blockIdx.x, tid = threadIdx.x;
    const float4 f = ((const float4*)(ws + (size_t)pu * 1024))[tid];
    const int v = tid >> 3, w0 = (tid & 7) * 4;
    tile[v][w0+0] = f.x; tile[v][w0+1] = f.y; tile[v][w0+2] = f.z; tile[v][w0+3] = f.w;

    // zero the output (2048*288 floats = 147456 float4s) while we wait
    float4 z4; z4.x = z4.y = z4.z = z4.w = 0.0f;
    for (int i = blockIdx.x * 256 + tid; i < 147456; i += 352 * 256)
        ((float4*)out)[i] = z4;

    __syncthreads();
    const int w = tid >> 3, vB = (tid & 7) * 4;
    ushort4 o;
    o.x = f2bf_bits(tile[vB+0][w]); o.y = f2bf_bits(tile[vB+1][w]);
    o.z = f2bf_bits(tile[vB+2][w]); o.w = f2bf_bits(tile[vB+3][w]);
    *(ushort4*)(wsT + (size_t)pu * 1024 + tid * 4) = o;
}

// ======================================================================
// Main kernel. Block 256 = 16 z x 16 v-pairs (build) = 4 MFMA waves
// (kh: slot-group) x (nt: w-half). Grid = 8 u-groups x 128 z-tiles,
// u-group in HIGH bits of blockIdx so the 8 blocks sharing output lines
// are 128 apart -> same XCD (128 % 8 == 0) -> atomic lines stay in one L2.
// LDS = shT only (35.8 KB) -> 4 blocks/CU; launch_bounds(256,4).
// ======================================================================

__launch_bounds__(256, 4)
__global__ void tp_mfma(const float* __restrict__ x1,
                        const float* __restrict__ x2,
                        const float* __restrict__ ws,
                        const unsigned short* __restrict__ wsT,
                        float* __restrict__ out, W3JArg w3j) {
    __shared__ unsigned shT[35 * 256];  // T[s][z(16)][v-word(16)], swizzled

    const int tid = threadIdx.x;
    const int l = tid & 63, wv = tid >> 6, kh = wv & 1, nt = wv >> 1;
    const int z0 = (blockIdx.x & 127) * 16;
    const int u0 = (blockIdx.x >> 7) * 4;
    const int tz = tid >> 4, vp = tid & 15, v0 = vp * 2;

    // ---- b0/b1 (x2 components for v0, v0+1) straight from global ----
    float b0[9], b1[9];
    {
        const float* xr = x2 + (size_t)(z0 + tz) * 288;
        float2 s0 = *(const float2*)(xr + v0);
        b0[0] = s0.x; b1[0] = s0.y;
        const float* p1 = xr + 32 + v0 * 3;
        float2 q0 = *(const float2*)(p1 + 0);
        float2 q1 = *(const float2*)(p1 + 2);
        float2 q2 = *(const float2*)(p1 + 4);
        b0[1] = q0.x; b0[2] = q0.y; b0[3] = q1.x;
        b1[1] = q1.y; b1[2] = q2.x; b1[3] = q2.y;
        const float* p2 = xr + 128 + v0 * 5;
        #pragma unroll
        for (int h = 0; h < 5; ++h) {
            float2 r = *(const float2*)(p2 + 2 * h);
            if (2 * h < 5) b0[4 + 2 * h] = r.x; else b1[4 + 2 * h - 5] = r.x;
            if (2 * h + 1 < 5) b0[5 + 2 * h] = r.y; else b1[4 + 2 * h - 4] = r.y;
        }
    }

    const float* x1r = x1 + (size_t)(z0 + tz) * 288;

    // swizzled LDS bases
    unsigned* dstT = shT + tz * 16 + (vp & 3) + ((((vp >> 2) + (tz >> 1)) & 3) << 2);
    const unsigned* tbase = shT + (l & 15) * 16 +
                            ((((l >> 4) + ((l & 15) >> 1)) & 3) << 2);

    const int w  = (l & 15) + nt * 16;   // N index (output mul w)
    const int vb = (l >> 4) * 8;         // K base (v)

    f32x4 acc[5];
    #pragma unroll
    for (int i = 0; i < 5; ++i) acc[i] = (f32x4)(0.0f);

    float a[2][9];
    load_a(x1r, u0, a[0]);

    for (int ui = 0; ui < 4; ++ui) {
        const int u = u0 + ui;
        const int cur = ui & 1;

        // B fragments issued at iter top -> in flight over barrier + build
        short8 bf[7];
        if (kh == 0) {
            #pragma unroll
            for (int p = 0; p < 7; ++p) bf[p] = load_bfrag<true>(ws, wsT, p, u, w, vb);
        } else {
            #pragma unroll
            for (int p = 0; p < 4; ++p) bf[p] = load_bfrag<true>(ws, wsT, 7 + p, u, w, vb);
        }

        // prefetch next-iter a (in flight over build + barrier + MFMA)
        if (ui < 3) load_a(x1r, u + 1, a[cur ^ 1]);

        __syncthreads();   // prior MFMA reads of shT complete
        build_all(w3j.c, a[cur], b0, b1, dstT);
        __syncthreads();

        // ---- MFMA phase (wave-specialized; same-target slots chain) ----
        if (kh == 0) {
            #pragma unroll
            for (int m = 0; m < 3; ++m) {
                short8 af = *(const short8*)(tbase + m * 256);
                acc[0] = __builtin_amdgcn_mfma_f32_16x16x32_bf16(af, bf[m], acc[0], 0, 0, 0);
            }
            #pragma unroll
            for (int g = 0; g < 3; ++g)
                #pragma unroll
                for (int m = 0; m < 4; ++m) {
                    short8 af = *(const short8*)(tbase + (3 + g*4 + m) * 256);
                    acc[1+g] = __builtin_amdgcn_mfma_f32_16x16x32_bf16(af, bf[3+m], acc[1+g], 0, 0, 0);
                }
        } else {
            #pragma unroll
            for (int g = 0; g < 5; ++g)
                #pragma unroll
                for (int m = 0; m < 4; ++m) {
                    short8 af = *(const short8*)(tbase + (15 + g*4 + m) * 256);
                    acc[g] = __builtin_amdgcn_mfma_f32_16x16x32_bf16(af, bf[m], acc[g], 0, 0, 0);
                }
        }
    }

    // ---- epilogue: D row = z0 + (l>>4)*4 + r, col = w ----
    const int zr = z0 + ((l >> 4) << 2);
    if (kh == 0) {
        #pragma unroll
        for (int r = 0; r < 4; ++r)
            atomicAdd(&out[(size_t)(zr + r) * 288 + w], acc[0][r]);
        #pragma unroll
        for (int k = 0; k < 3; ++k)
            #pragma unroll
            for (int r = 0; r < 4; ++r)
                atomicAdd(&out[(size_t)(zr + r) * 288 + 32 + w*3 + k], acc[1+k][r]);
    } else {
        #pragma unroll
        for (int k = 0; k < 5; ++k)
            #pragma unroll
            for (int r = 0; r < 4; ++r)
                atomicAdd(&out[(size_t)(zr + r) * 288 + 128 + w*5 + k], acc[k][r]);
    }
}

// Fallback (no workspace): identical but b-frags converted from fp32 ws.
__launch_bounds__(256, 4)
__global__ void tp_mfma_nowst(const float* __restrict__ x1,
                              const float* __restrict__ x2,
                              const float* __restrict__ ws,
                              float* __restrict__ out, W3JArg w3j) {
    __shared__ unsigned shT[35 * 256];
    const int tid = threadIdx.x;
    const int l = tid & 63, wv = tid >> 6, kh = wv & 1, nt = wv >> 1;
    const int z0 = (blockIdx.x & 127) * 16;
    const int u0 = (blockIdx.x >> 7) * 4;
    const int tz = tid >> 4, vp = tid & 15, v0 = vp * 2;

    float b0[9], b1[9];
    {
        const float* xr = x2 + (size_t)(z0 + tz) * 288;
        float2 s0 = *(const float2*)(xr + v0);
        b0[0] = s0.x; b1[0] = s0.y;
        const float* p1 = xr + 32 + v0 * 3;
        float2 q0 = *(const float2*)(p1 + 0);
        float2 q1 = *(const float2*)(p1 + 2);
        float2 q2 = *(const float2*)(p1 + 4);
        b0[1] = q0.x; b0[2] = q0.y; b0[3] = q1.x;
        b1[1] = q1.y; b1[2] = q2.x; b1[3] = q2.y;
        const float* p2 = xr + 128 + v0 * 5;
        #pragma unroll
        for (int h = 0; h < 5; ++h) {
            float2 r = *(const float2*)(p2 + 2 * h);
            if (2 * h < 5) b0[4 + 2 * h] = r.x; else b1[4 + 2 * h - 5] = r.x;
            if (2 * h + 1 < 5) b0[5 + 2 * h] = r.y; else b1[4 + 2 * h - 4] = r.y;
        }
    }
    const float* x1r = x1 + (size_t)(z0 + tz) * 288;
    unsigned* dstT = shT + tz * 16 + (vp & 3) + ((((vp >> 2) + (tz >> 1)) & 3) << 2);
    const unsigned* tbase = shT + (l & 15) * 16 +
                            ((((l >> 4) + ((l & 15) >> 1)) & 3) << 2);
    const int w  = (l & 15) + nt * 16;
    const int vb = (l >> 4) * 8;

    f32x4 acc[5];
    #pragma unroll
    for (int i = 0; i < 5; ++i) acc[i] = (f32x4)(0.0f);
    float a[2][9];
    load_a(x1r, u0, a[0]);

    for (int ui = 0; ui < 4; ++ui) {
        const int u = u0 + ui;
        const int cur = ui & 1;
        short8 bf[7];
        if (kh == 0) {
            #pragma unroll
            for (int p = 0; p < 7; ++p) bf[p] = load_bfrag<false>(ws, nullptr, p, u, w, vb);
        } else {
            #pragma unroll
            for (int p = 0; p < 4; ++p) bf[p] = load_bfrag<false>(ws, nullptr, 7 + p, u, w, vb);
        }
        if (ui < 3) load_a(x1r, u + 1, a[cur ^ 1]);
        __syncthreads();
        build_all(w3j.c, a[cur], b0, b1, dstT);
        __syncthreads();
        if (kh == 0) {
            #pragma unroll
            for (int m = 0; m < 3; ++m) {
                short8 af = *(const short8*)(tbase + m * 256);
                acc[0] = __builtin_amdgcn_mfma_f32_16x16x32_bf16(af, bf[m], acc[0], 0, 0, 0);
            }
            #pragma unroll
            for (int g = 0; g < 3; ++g)
                #pragma unroll
                for (int m = 0; m < 4; ++m) {
                    short8 af = *(const short8*)(tbase + (3 + g*4 + m) * 256);
                    acc[1+g] = __builtin_amdgcn_mfma_f32_16x16x32_bf16(af, bf[3+m], acc[1+g], 0, 0, 0);
                }
        } else {
            #pragma unroll
            for (int g = 0; g < 5; ++g)
                #pragma unroll
                for (int m = 0; m < 4; ++m) {
                    short8 af = *(const short8*)(tbase + (15 + g*4 + m) * 256);
                    acc[g] = __builtin_amdgcn_mfma_f32_16x16x32_bf16(af, bf[m], acc[g], 0, 0, 0);
                }
        }
    }
    const int zr = z0 + ((l >> 4) << 2);
    if (kh == 0) {
        #pragma unroll
        for (int r = 0; r < 4; ++r)
            atomicAdd(&out[(size_t)(zr + r) * 288 + w], acc[0][r]);
        #pragma unroll
        for (int k = 0; k < 3; ++k)
            #pragma unroll
            for (int r = 0; r < 4; ++r)
                atomicAdd(&out[(size_t)(zr + r) * 288 + 32 + w*3 + k], acc[1+k][r]);
    } else {
        #pragma unroll
        for (int k = 0; k < 5; ++k)
            #pragma unroll
            for (int r = 0; r < 4; ++r)
                atomicAdd(&out[(size_t)(zr + r) * 288 + 128 + w*5 + k], acc[k][r]);
    }
}

// ======================================================================

extern "C" void kernel_launch(void* const* d_in, const int* in_sizes, int n_in,
                              void* d_out, int out_size, void* d_ws, size_t ws_size,
                              hipStream_t stream) {
    const float* x1 = (const float*)d_in[0];
    const float* x2 = (const float*)d_in[1];
    const float* ws = (const float*)d_in[2];
    float* out = (float*)d_out;

    static const W3JArg arg = build_w3j_sparse();

    const int B = in_sizes[0] / 288;          // 2048
    const int grid = 8 * (B / 16);            // 8 u-groups x 128 z-tiles

    const size_t wst_bytes = (size_t)11 * 32 * 32 * 32 * 2;
    unsigned short* wsT = (unsigned short*)d_ws;
    if (ws_size >= wst_bytes) {
        ws_prep<<<dim3(11 * 32), dim3(256), 0, stream>>>(ws, wsT, out);
        tp_mfma<<<dim3(grid), dim3(256), 0, stream>>>(x1, x2, ws, wsT, out, arg);
    } else {
        hipMemsetAsync(out, 0, (size_t)out_size * sizeof(float), stream);
        tp_mfma_nowst<<<dim3(grid), dim3(256), 0, stream>>>(x1, x2, ws, out, arg);
    }
}

// Round 6
// 88.733 us; speedup vs baseline: 1.4013x; 1.4013x over previous
//
#include <hip/hip_runtime.h>
#include <hip/hip_bf16.h>
#include <cmath>
#include <complex>
#include <algorithm>

// ======================================================================
// Host-side exact port of the reference e3nn wigner_3j (unit Frobenius
// norm, real basis, (-1j)^l phase). Computed once, passed by value.
// ======================================================================

typedef std::complex<double> cd;

static double factd(int n) { double r = 1; for (int i = 2; i <= n; ++i) r *= i; return r; }

static double su2_cg(int j1, int m1, int j2, int m2, int j3, int m3) {
    if (m3 != m1 + m2) return 0.0;
    int vmin = std::max(std::max(-j1 + j2 + m3, -j1 + m1), 0);
    int vmax = std::min(std::min(j2 + j3 + m1, j3 - j1 + j2), j3 + m3);
    double C = std::sqrt((2.0 * j3 + 1.0) *
        (factd(j3 + j1 - j2) * factd(j3 - j1 + j2) * factd(j1 + j2 - j3) *
         factd(j3 + m3) * factd(j3 - m3)) /
        (factd(j1 + j2 + j3 + 1) * factd(j1 - m1) * factd(j1 + m1) *
         factd(j2 - m2) * factd(j2 + m2)));
    double S = 0.0;
    for (int v = vmin; v <= vmax; ++v) {
        double sgn = ((v + j2 + m2) & 1) ? -1.0 : 1.0;
        S += sgn * (factd(j2 + j3 + m1 - v) * factd(j1 - m1 + v)) /
             (factd(v) * factd(j3 - j1 + j2 - v) * factd(j3 + m3 - v) *
              factd(v + j1 - j2 - m3));
    }
    return C * S;
}

static void qmat(int l, cd* q) {
    int n = 2 * l + 1;
    for (int i = 0; i < n * n; ++i) q[i] = cd(0, 0);
    const double s = 1.0 / std::sqrt(2.0);
    for (int m = -l; m < 0; ++m) {
        q[(l + m) * n + (l - m)] = cd(s, 0);
        q[(l + m) * n + (l + m)] = cd(0, -s);
    }
    q[l * n + l] = cd(1, 0);
    for (int m = 1; m <= l; ++m) {
        double sg = (m & 1) ? -1.0 : 1.0;
        q[(l + m) * n + (l + m)] = cd(sg * s, 0);
        q[(l + m) * n + (l - m)] = cd(0, sg * s);
    }
    cd ph(1, 0);
    for (int t = 0; t < l; ++t) ph *= cd(0, -1);
    for (int i = 0; i < n * n; ++i) q[i] *= ph;
}

static void wigner3j_dense(int l1, int l2, int l3, double* outp) {
    int n1 = 2 * l1 + 1, n2 = 2 * l2 + 1, n3 = 2 * l3 + 1;
    double cg[125];
    for (int i = 0; i < n1 * n2 * n3; ++i) cg[i] = 0.0;
    for (int m1 = -l1; m1 <= l1; ++m1)
        for (int m2 = -l2; m2 <= l2; ++m2) {
            int m3 = m1 + m2;
            if (std::abs(m3) <= l3)
                cg[((l1 + m1) * n2 + (l2 + m2)) * n3 + (l3 + m3)] =
                    su2_cg(l1, m1, l2, m2, l3, m3);
        }
    cd q1[25], q2[25], q3[25];
    qmat(l1, q1); qmat(l2, q2); qmat(l3, q3);
    double norm2 = 0.0;
    for (int j = 0; j < n1; ++j)
        for (int l = 0; l < n2; ++l)
            for (int m = 0; m < n3; ++m) {
                cd sum(0, 0);
                for (int i = 0; i < n1; ++i)
                    for (int k = 0; k < n2; ++k)
                        for (int n = 0; n < n3; ++n) {
                            double g = cg[(i * n2 + k) * n3 + n];
                            if (g != 0.0)
                                sum += q1[i * n1 + j] * q2[k * n2 + l] *
                                       std::conj(q3[n * n3 + m]) * g;
                        }
                outp[(j * n2 + l) * n3 + m] = sum.real();
                norm2 += sum.real() * sum.real();
            }
    double inv = 1.0 / std::sqrt(norm2);
    for (int t = 0; t < n1 * n2 * n3; ++t) outp[t] *= inv;
}

// ======================================================================
// Sparsity pattern of the real-basis w3j (structural nonzeros).
// ======================================================================

struct E3 { unsigned char i, j, k; };

constexpr E3 PAT_P0[1]  = {{0,0,0}};
constexpr E3 PAT_P1[3]  = {{0,0,0},{1,1,0},{2,2,0}};
constexpr E3 PAT_P2[5]  = {{0,0,0},{1,1,0},{2,2,0},{3,3,0},{4,4,0}};
constexpr E3 PAT_P3[3]  = {{0,0,0},{0,1,1},{0,2,2}};
constexpr E3 PAT_P4[3]  = {{0,0,0},{1,0,1},{2,0,2}};
constexpr E3 PAT_P5[11] = {{1,2,1},{1,3,2},{1,1,0},{2,2,2},{0,2,0},{2,3,1},
                           {0,1,1},{2,4,2},{0,0,2},{2,0,0},{0,4,0}};
constexpr E3 PAT_P6[11] = {{2,1,1},{2,2,2},{2,0,0},{3,1,2},{1,1,0},{3,2,1},
                           {1,0,1},{4,2,2},{0,0,2},{4,0,0},{0,2,0}};
constexpr E3 PAT_P7[5]  = {{0,0,0},{0,1,1},{0,2,2},{0,3,3},{0,4,4}};
constexpr E3 PAT_P8[11] = {{1,1,2},{1,2,3},{1,0,1},{2,1,3},{0,1,1},{2,2,2},
                           {0,0,2},{2,2,4},{0,0,4},{2,0,0},{0,2,0}};
constexpr E3 PAT_P9[5]  = {{0,0,0},{1,0,1},{2,0,2},{3,0,3},{4,0,4}};
constexpr E3 PAT_P10[25]= {{2,2,2},{2,3,3},{2,1,1},{2,4,4},{2,0,0},{3,2,3},
                           {1,2,1},{3,3,2},{1,1,2},{3,3,4},{1,1,4},{3,1,0},
                           {1,3,0},{3,4,3},{1,0,3},{3,0,1},{1,4,1},{4,2,4},
                           {0,2,0},{4,3,3},{0,1,3},{4,1,1},{0,3,1},{4,4,2},
                           {0,0,2}};

constexpr int OFF_P[11] = {0, 1, 4, 9, 12, 15, 26, 37, 42, 53, 58};

struct W3JArg { float c[83]; };

static W3JArg build_w3j_sparse() {
    struct PD { const E3* pat; int ne; int l1, l2, lo; double alpha; };
    const double a0 = std::sqrt(1.0/3072.0), a1 = std::sqrt(3.0/4096.0),
                 a2 = std::sqrt(5.0/4096.0);
    const PD pd[11] = {
        {PAT_P0, 1, 0,0,0, a0}, {PAT_P1, 3, 1,1,0, a0}, {PAT_P2, 5, 2,2,0, a0},
        {PAT_P3, 3, 0,1,1, a1}, {PAT_P4, 3, 1,0,1, a1}, {PAT_P5,11, 1,2,1, a1},
        {PAT_P6,11, 2,1,1, a1}, {PAT_P7, 5, 0,2,2, a2}, {PAT_P8,11, 1,1,2, a2},
        {PAT_P9, 5, 2,0,2, a2}, {PAT_P10,25,2,2,2, a2}
    };
    W3JArg arg;
    for (int p = 0; p < 11; ++p) {
        double dense[125];
        wigner3j_dense(pd[p].l1, pd[p].l2, pd[p].lo, dense);
        int n2 = 2*pd[p].l2+1, n3 = 2*pd[p].lo+1;
        for (int e = 0; e < pd[p].ne; ++e) {
            const E3& t = pd[p].pat[e];
            arg.c[OFF_P[p] + e] =
                (float)(dense[(t.i * n2 + t.j) * n3 + t.k] * pd[p].alpha);
        }
    }
    return arg;
}

// ======================================================================
// Device
// ======================================================================

typedef __attribute__((ext_vector_type(8))) short short8;
typedef __attribute__((ext_vector_type(4))) float f32x4;

__device__ __forceinline__ unsigned short f2bf_bits(float f) {
    __hip_bfloat16 h = __float2bfloat16(f);
    unsigned short u; __builtin_memcpy(&u, &h, 2); return u;
}

__device__ __forceinline__ unsigned pack2(float lo, float hi) {
    float2 f2; f2.x = lo; f2.y = hi;
    __hip_bfloat162 pk = __float22bfloat162_rn(f2);
    unsigned u; __builtin_memcpy(&u, &pk, 4); return u;
}

// One path: ca_e = c_e*a[i_e] once, then t0/t1 FMAs; pack + LDS store.
template<int NE, int A1, int A2, int D3, int SBASE, int SSTR>
__device__ __forceinline__ void do_path(const E3 (&pat)[NE],
                                        const float* __restrict__ cs,
                                        const float* a, const float* b0,
                                        const float* b1,
                                        unsigned* __restrict__ dst) {
    float ca[NE];
    #pragma unroll
    for (int e = 0; e < NE; ++e) ca[e] = cs[e] * a[A1 + pat[e].i];
    float t0[D3], t1[D3];
    #pragma unroll
    for (int k = 0; k < D3; ++k) { t0[k] = 0.0f; t1[k] = 0.0f; }
    #pragma unroll
    for (int e = 0; e < NE; ++e) {
        const int k = pat[e].k;
        t0[k] = fmaf(ca[e], b0[A2 + pat[e].j], t0[k]);
        t1[k] = fmaf(ca[e], b1[A2 + pat[e].j], t1[k]);
    }
    #pragma unroll
    for (int k = 0; k < D3; ++k)
        dst[(SBASE + k * SSTR) * 256] = pack2(t0[k], t1[k]);
}

__device__ __forceinline__ void build_all(const float* __restrict__ cs,
                                          const float* a, const float* b0,
                                          const float* b1,
                                          unsigned* __restrict__ dst) {
    do_path< 1,0,0,1, 0,1>(PAT_P0,  cs +  0, a, b0, b1, dst);
    do_path< 3,1,1,1, 1,1>(PAT_P1,  cs +  1, a, b0, b1, dst);
    do_path< 5,4,4,1, 2,1>(PAT_P2,  cs +  4, a, b0, b1, dst);
    do_path< 3,0,1,3, 3,4>(PAT_P3,  cs +  9, a, b0, b1, dst);
    do_path< 3,1,0,3, 4,4>(PAT_P4,  cs + 12, a, b0, b1, dst);
    do_path<11,1,4,3, 5,4>(PAT_P5,  cs + 15, a, b0, b1, dst);
    do_path<11,4,1,3, 6,4>(PAT_P6,  cs + 26, a, b0, b1, dst);
    do_path< 5,0,4,5,15,4>(PAT_P7,  cs + 37, a, b0, b1, dst);
    do_path<11,1,1,5,16,4>(PAT_P8,  cs + 42, a, b0, b1, dst);
    do_path< 5,4,0,5,17,4>(PAT_P9,  cs + 53, a, b0, b1, dst);
    do_path<25,4,4,5,18,4>(PAT_P10, cs + 58, a, b0, b1, dst);
}

__device__ __forceinline__ void load_a(const float* __restrict__ x1r, int u,
                                       float* a) {
    a[0] = x1r[u];
    #pragma unroll
    for (int i = 0; i < 3; ++i) a[1 + i] = x1r[32 + u * 3 + i];
    #pragma unroll
    for (int i = 0; i < 5; ++i) a[4 + i] = x1r[128 + u * 5 + i];
}

// B fragment: wsT[p][u][w][v] bf16; lane: n = l&15 -> w, k = (l>>4)*8+j -> v
template<bool USE_WST>
__device__ __forceinline__ short8 load_bfrag(const float* __restrict__ ws,
                                             const unsigned short* __restrict__ wsT,
                                             int p, int u, int w, int vbase) {
    if constexpr (USE_WST) {
        return *(const short8*)(wsT + (((size_t)(p*32+u)*32 + w)*32 + vbase));
    } else {
        short8 r;
        #pragma unroll
        for (int j = 0; j < 8; ++j) {
            float f = ws[((size_t)(p*32+u)*32 + (vbase+j))*32 + w];
            r[j] = (short)f2bf_bits(f);
        }
        return r;
    }
}

// ws prep: wsT[p][u][w][v] bf16 <- ws[p][u][v][w] fp32
__global__ void ws_prep(const float* __restrict__ ws,
                        unsigned short* __restrict__ wsT) {
    __shared__ float tile[32][33];
    const int pu = blockIdx.x, tid = threadIdx.x;
    const float4 f = ((const float4*)(ws + (size_t)pu * 1024))[tid];
    const int v = tid >> 3, w0 = (tid & 7) * 4;
    tile[v][w0+0] = f.x; tile[v][w0+1] = f.y; tile[v][w0+2] = f.z; tile[v][w0+3] = f.w;
    __syncthreads();
    const int w = tid >> 3, vB = (tid & 7) * 4;
    ushort4 o;
    o.x = f2bf_bits(tile[vB+0][w]); o.y = f2bf_bits(tile[vB+1][w]);
    o.z = f2bf_bits(tile[vB+2][w]); o.w = f2bf_bits(tile[vB+3][w]);
    *(ushort4*)(wsT + (size_t)pu * 1024 + tid * 4) = o;
}

// ======================================================================
// Main kernel. Block 256 = 16 z x 16 v-pairs (build) = 4 MFMA waves
// (kh: slot-group) x (nt: w-half). Grid = 8 u-groups x (B/16) z-tiles.
// Epilogue: contention-free coalesced fp32 partial stores to d_ws:
//   part[ug][zt][comp(9)][zi(16)][w(32)]   (comp: io0=0, io1 k->1+k, io2 k->4+k)
// ======================================================================

__launch_bounds__(256, 4)
__global__ void tp_mfma(const float* __restrict__ x1,
                        const float* __restrict__ x2,
                        const unsigned short* __restrict__ wsT,
                        float* __restrict__ part, int ZT, W3JArg w3j) {
    __shared__ unsigned shT[35 * 256];  // T[s][z(16)][v-word(16)], swizzled

    const int tid = threadIdx.x;
    const int l = tid & 63, wv = tid >> 6, kh = wv & 1, nt = wv >> 1;
    const int zt = blockIdx.x & (ZT - 1);
    const int ug = blockIdx.x / ZT;
    const int z0 = zt * 16, u0 = ug * 4;
    const int tz = tid >> 4, vp = tid & 15, v0 = vp * 2;

    // ---- b0/b1 (x2 components for v0, v0+1) straight from global ----
    float b0[9], b1[9];
    {
        const float* xr = x2 + (size_t)(z0 + tz) * 288;
        float2 s0 = *(const float2*)(xr + v0);
        b0[0] = s0.x; b1[0] = s0.y;
        const float* p1 = xr + 32 + v0 * 3;
        float2 q0 = *(const float2*)(p1 + 0);
        float2 q1 = *(const float2*)(p1 + 2);
        float2 q2 = *(const float2*)(p1 + 4);
        b0[1] = q0.x; b0[2] = q0.y; b0[3] = q1.x;
        b1[1] = q1.y; b1[2] = q2.x; b1[3] = q2.y;
        const float* p2 = xr + 128 + v0 * 5;
        #pragma unroll
        for (int h = 0; h < 5; ++h) {
            float2 r = *(const float2*)(p2 + 2 * h);
            if (2 * h < 5) b0[4 + 2 * h] = r.x; else b1[4 + 2 * h - 5] = r.x;
            if (2 * h + 1 < 5) b0[5 + 2 * h] = r.y; else b1[4 + 2 * h - 4] = r.y;
        }
    }

    const float* x1r = x1 + (size_t)(z0 + tz) * 288;

    // swizzled LDS bases
    unsigned* dstT = shT + tz * 16 + (vp & 3) + ((((vp >> 2) + (tz >> 1)) & 3) << 2);
    const unsigned* tbase = shT + (l & 15) * 16 +
                            ((((l >> 4) + ((l & 15) >> 1)) & 3) << 2);

    const int w  = (l & 15) + nt * 16;   // N index (output mul w)
    const int vb = (l >> 4) * 8;         // K base (v)

    f32x4 acc[5];
    #pragma unroll
    for (int i = 0; i < 5; ++i) acc[i] = (f32x4)(0.0f);

    float a[2][9];
    load_a(x1r, u0, a[0]);

    for (int ui = 0; ui < 4; ++ui) {
        const int u = u0 + ui;
        const int cur = ui & 1;

        // B fragments issued at iter top -> in flight over barrier + build
        short8 bf[7];
        if (kh == 0) {
            #pragma unroll
            for (int p = 0; p < 7; ++p) bf[p] = load_bfrag<true>(nullptr, wsT, p, u, w, vb);
        } else {
            #pragma unroll
            for (int p = 0; p < 4; ++p) bf[p] = load_bfrag<true>(nullptr, wsT, 7 + p, u, w, vb);
        }

        // prefetch next-iter a (in flight over build + barrier + MFMA)
        if (ui < 3) load_a(x1r, u + 1, a[cur ^ 1]);

        __syncthreads();   // prior MFMA reads of shT complete
        build_all(w3j.c, a[cur], b0, b1, dstT);
        __syncthreads();

        // ---- MFMA phase (wave-specialized; same-target slots chain) ----
        if (kh == 0) {
            #pragma unroll
            for (int m = 0; m < 3; ++m) {
                short8 af = *(const short8*)(tbase + m * 256);
                acc[0] = __builtin_amdgcn_mfma_f32_16x16x32_bf16(af, bf[m], acc[0], 0, 0, 0);
            }
            #pragma unroll
            for (int g = 0; g < 3; ++g)
                #pragma unroll
                for (int m = 0; m < 4; ++m) {
                    short8 af = *(const short8*)(tbase + (3 + g*4 + m) * 256);
                    acc[1+g] = __builtin_amdgcn_mfma_f32_16x16x32_bf16(af, bf[3+m], acc[1+g], 0, 0, 0);
                }
        } else {
            #pragma unroll
            for (int g = 0; g < 5; ++g)
                #pragma unroll
                for (int m = 0; m < 4; ++m) {
                    short8 af = *(const short8*)(tbase + (15 + g*4 + m) * 256);
                    acc[g] = __builtin_amdgcn_mfma_f32_16x16x32_bf16(af, bf[m], acc[g], 0, 0, 0);
                }
        }
    }

    // ---- epilogue: coalesced partial stores (no atomics, no contention) ----
    // D row = (l>>4)*4 + r, col = w. part plane = 512 floats per comp.
    float* pb = part + ((size_t)(ug * ZT + zt) * 9) * 512;
    const int zi4 = (l >> 4) << 2;
    if (kh == 0) {
        #pragma unroll
        for (int r = 0; r < 4; ++r)
            pb[(zi4 + r) * 32 + w] = acc[0][r];
        #pragma unroll
        for (int k = 0; k < 3; ++k)
            #pragma unroll
            for (int r = 0; r < 4; ++r)
                pb[(1 + k) * 512 + (zi4 + r) * 32 + w] = acc[1 + k][r];
    } else {
        #pragma unroll
        for (int k = 0; k < 5; ++k)
            #pragma unroll
            for (int r = 0; r < 4; ++r)
                pb[(4 + k) * 512 + (zi4 + r) * 32 + w] = acc[k][r];
    }
}

// ======================================================================
// Reduce: out[z][col] = sum_ug part[ug][zt][comp][zi][w].
// Grid = ZT*9 blocks; block 256 threads, 2 elements each (512 = 16z x 32w).
// Reads fully coalesced (4B/lane across 8 streams); writes small (2.4 MB).
// ======================================================================

__global__ void reduce_out(const float* __restrict__ part,
                           float* __restrict__ out, int ZT) {
    const int bid = blockIdx.x;
    const int zt = bid / 9, comp = bid - zt * 9;
    const int tid = threadIdx.x;
    #pragma unroll
    for (int h = 0; h < 2; ++h) {
        const int e = tid + h * 256;          // 0..511
        const int zi = e >> 5, w = e & 31;
        float s = 0.0f;
        #pragma unroll
        for (int g = 0; g < 8; ++g)
            s += part[((size_t)(g * ZT + zt) * 9 + comp) * 512 + e];
        int col;
        if (comp == 0)      col = w;
        else if (comp < 4)  col = 32 + w * 3 + (comp - 1);
        else                col = 128 + w * 5 + (comp - 4);
        out[(size_t)(zt * 16 + zi) * 288 + col] = s;
    }
}

// ======================================================================
// Fallback (workspace too small): atomic epilogue, fp32 ws, zeroed out.
// ======================================================================

__launch_bounds__(256, 4)
__global__ void tp_mfma_atomic(const float* __restrict__ x1,
                               const float* __restrict__ x2,
                               const float* __restrict__ ws,
                               float* __restrict__ out, int ZT, W3JArg w3j) {
    __shared__ unsigned shT[35 * 256];
    const int tid = threadIdx.x;
    const int l = tid & 63, wv = tid >> 6, kh = wv & 1, nt = wv >> 1;
    const int zt = blockIdx.x & (ZT - 1);
    const int ug = blockIdx.x / ZT;
    const int z0 = zt * 16, u0 = ug * 4;
    const int tz = tid >> 4, vp = tid & 15, v0 = vp * 2;

    float b0[9], b1[9];
    {
        const float* xr = x2 + (size_t)(z0 + tz) * 288;
        float2 s0 = *(const float2*)(xr + v0);
        b0[0] = s0.x; b1[0] = s0.y;
        const float* p1 = xr + 32 + v0 * 3;
        float2 q0 = *(const float2*)(p1 + 0);
        float2 q1 = *(const float2*)(p1 + 2);
        float2 q2 = *(const float2*)(p1 + 4);
        b0[1] = q0.x; b0[2] = q0.y; b0[3] = q1.x;
        b1[1] = q1.y; b1[2] = q2.x; b1[3] = q2.y;
        const float* p2 = xr + 128 + v0 * 5;
        #pragma unroll
        for (int h = 0; h < 5; ++h) {
            float2 r = *(const float2*)(p2 + 2 * h);
            if (2 * h < 5) b0[4 + 2 * h] = r.x; else b1[4 + 2 * h - 5] = r.x;
            if (2 * h + 1 < 5) b0[5 + 2 * h] = r.y; else b1[4 + 2 * h - 4] = r.y;
        }
    }
    const float* x1r = x1 + (size_t)(z0 + tz) * 288;
    unsigned* dstT = shT + tz * 16 + (vp & 3) + ((((vp >> 2) + (tz >> 1)) & 3) << 2);
    const unsigned* tbase = shT + (l & 15) * 16 +
                            ((((l >> 4) + ((l & 15) >> 1)) & 3) << 2);
    const int w  = (l & 15) + nt * 16;
    const int vb = (l >> 4) * 8;

    f32x4 acc[5];
    #pragma unroll
    for (int i = 0; i < 5; ++i) acc[i] = (f32x4)(0.0f);
    float a[2][9];
    load_a(x1r, u0, a[0]);

    for (int ui = 0; ui < 4; ++ui) {
        const int u = u0 + ui;
        const int cur = ui & 1;
        short8 bf[7];
        if (kh == 0) {
            #pragma unroll
            for (int p = 0; p < 7; ++p) bf[p] = load_bfrag<false>(ws, nullptr, p, u, w, vb);
        } else {
            #pragma unroll
            for (int p = 0; p < 4; ++p) bf[p] = load_bfrag<false>(ws, nullptr, 7 + p, u, w, vb);
        }
        if (ui < 3) load_a(x1r, u + 1, a[cur ^ 1]);
        __syncthreads();
        build_all(w3j.c, a[cur], b0, b1, dstT);
        __syncthreads();
        if (kh == 0) {
            #pragma unroll
            for (int m = 0; m < 3; ++m) {
                short8 af = *(const short8*)(tbase + m * 256);
                acc[0] = __builtin_amdgcn_mfma_f32_16x16x32_bf16(af, bf[m], acc[0], 0, 0, 0);
            }
            #pragma unroll
            for (int g = 0; g < 3; ++g)
                #pragma unroll
                for (int m = 0; m < 4; ++m) {
                    short8 af = *(const short8*)(tbase + (3 + g*4 + m) * 256);
                    acc[1+g] = __builtin_amdgcn_mfma_f32_16x16x32_bf16(af, bf[3+m], acc[1+g], 0, 0, 0);
                }
        } else {
            #pragma unroll
            for (int g = 0; g < 5; ++g)
                #pragma unroll
                for (int m = 0; m < 4; ++m) {
                    short8 af = *(const short8*)(tbase + (15 + g*4 + m) * 256);
                    acc[g] = __builtin_amdgcn_mfma_f32_16x16x32_bf16(af, bf[m], acc[g], 0, 0, 0);
                }
        }
    }
    const int zr = z0 + ((l >> 4) << 2);
    if (kh == 0) {
        #pragma unroll
        for (int r = 0; r < 4; ++r)
            atomicAdd(&out[(size_t)(zr + r) * 288 + w], acc[0][r]);
        #pragma unroll
        for (int k = 0; k < 3; ++k)
            #pragma unroll
            for (int r = 0; r < 4; ++r)
                atomicAdd(&out[(size_t)(zr + r) * 288 + 32 + w*3 + k], acc[1+k][r]);
    } else {
        #pragma unroll
        for (int k = 0; k < 5; ++k)
            #pragma unroll
            for (int r = 0; r < 4; ++r)
                atomicAdd(&out[(size_t)(zr + r) * 288 + 128 + w*5 + k], acc[k][r]);
    }
}

// ======================================================================

extern "C" void kernel_launch(void* const* d_in, const int* in_sizes, int n_in,
                              void* d_out, int out_size, void* d_ws, size_t ws_size,
                              hipStream_t stream) {
    const float* x1 = (const float*)d_in[0];
    const float* x2 = (const float*)d_in[1];
    const float* ws = (const float*)d_in[2];
    float* out = (float*)d_out;

    static const W3JArg arg = build_w3j_sparse();

    const int B = in_sizes[0] / 288;          // 2048
    const int ZT = B / 16;                    // 128 z-tiles
    const int grid_main = 8 * ZT;             // 8 u-groups

    const size_t wst_bytes  = (size_t)11 * 32 * 32 * 32 * 2;   // 720 KB
    const size_t part_off_b = 786432;                          // 768 KB aligned
    const size_t part_bytes = (size_t)8 * ZT * 9 * 512 * 4;    // 18.9 MB

    if (ws_size >= part_off_b + part_bytes) {
        unsigned short* wsT = (unsigned short*)d_ws;
        float* part = (float*)((char*)d_ws + part_off_b);
        ws_prep<<<dim3(11 * 32), dim3(256), 0, stream>>>(ws, wsT);
        tp_mfma<<<dim3(grid_main), dim3(256), 0, stream>>>(x1, x2, wsT, part, ZT, arg);
        reduce_out<<<dim3(ZT * 9), dim3(256), 0, stream>>>(part, out, ZT);
    } else {
        hipMemsetAsync(out, 0, (size_t)out_size * sizeof(float), stream);
        tp_mfma_atomic<<<dim3(grid_main), dim3(256), 0, stream>>>(x1, x2, ws, out, ZT, arg);
    }
    (void)wst_bytes;
}

// Round 7
// 88.611 us; speedup vs baseline: 1.4032x; 1.0014x over previous
//
#include <hip/hip_runtime.h>
#include <hip/hip_bf16.h>
#include <cmath>
#include <complex>
#include <algorithm>

// ======================================================================
// Host-side exact port of the reference e3nn wigner_3j (unit Frobenius
// norm, real basis, (-1j)^l phase). Computed once, passed by value.
// ======================================================================

typedef std::complex<double> cd;

static double factd(int n) { double r = 1; for (int i = 2; i <= n; ++i) r *= i; return r; }

static double su2_cg(int j1, int m1, int j2, int m2, int j3, int m3) {
    if (m3 != m1 + m2) return 0.0;
    int vmin = std::max(std::max(-j1 + j2 + m3, -j1 + m1), 0);
    int vmax = std::min(std::min(j2 + j3 + m1, j3 - j1 + j2), j3 + m3);
    double C = std::sqrt((2.0 * j3 + 1.0) *
        (factd(j3 + j1 - j2) * factd(j3 - j1 + j2) * factd(j1 + j2 - j3) *
         factd(j3 + m3) * factd(j3 - m3)) /
        (factd(j1 + j2 + j3 + 1) * factd(j1 - m1) * factd(j1 + m1) *
         factd(j2 - m2) * factd(j2 + m2)));
    double S = 0.0;
    for (int v = vmin; v <= vmax; ++v) {
        double sgn = ((v + j2 + m2) & 1) ? -1.0 : 1.0;
        S += sgn * (factd(j2 + j3 + m1 - v) * factd(j1 - m1 + v)) /
             (factd(v) * factd(j3 - j1 + j2 - v) * factd(j3 + m3 - v) *
              factd(v + j1 - j2 - m3));
    }
    return C * S;
}

static void qmat(int l, cd* q) {
    int n = 2 * l + 1;
    for (int i = 0; i < n * n; ++i) q[i] = cd(0, 0);
    const double s = 1.0 / std::sqrt(2.0);
    for (int m = -l; m < 0; ++m) {
        q[(l + m) * n + (l - m)] = cd(s, 0);
        q[(l + m) * n + (l + m)] = cd(0, -s);
    }
    q[l * n + l] = cd(1, 0);
    for (int m = 1; m <= l; ++m) {
        double sg = (m & 1) ? -1.0 : 1.0;
        q[(l + m) * n + (l + m)] = cd(sg * s, 0);
        q[(l + m) * n + (l - m)] = cd(0, sg * s);
    }
    cd ph(1, 0);
    for (int t = 0; t < l; ++t) ph *= cd(0, -1);
    for (int i = 0; i < n * n; ++i) q[i] *= ph;
}

static void wigner3j_dense(int l1, int l2, int l3, double* outp) {
    int n1 = 2 * l1 + 1, n2 = 2 * l2 + 1, n3 = 2 * l3 + 1;
    double cg[125];
    for (int i = 0; i < n1 * n2 * n3; ++i) cg[i] = 0.0;
    for (int m1 = -l1; m1 <= l1; ++m1)
        for (int m2 = -l2; m2 <= l2; ++m2) {
            int m3 = m1 + m2;
            if (std::abs(m3) <= l3)
                cg[((l1 + m1) * n2 + (l2 + m2)) * n3 + (l3 + m3)] =
                    su2_cg(l1, m1, l2, m2, l3, m3);
        }
    cd q1[25], q2[25], q3[25];
    qmat(l1, q1); qmat(l2, q2); qmat(l3, q3);
    double norm2 = 0.0;
    for (int j = 0; j < n1; ++j)
        for (int l = 0; l < n2; ++l)
            for (int m = 0; m < n3; ++m) {
                cd sum(0, 0);
                for (int i = 0; i < n1; ++i)
                    for (int k = 0; k < n2; ++k)
                        for (int n = 0; n < n3; ++n) {
                            double g = cg[(i * n2 + k) * n3 + n];
                            if (g != 0.0)
                                sum += q1[i * n1 + j] * q2[k * n2 + l] *
                                       std::conj(q3[n * n3 + m]) * g;
                        }
                outp[(j * n2 + l) * n3 + m] = sum.real();
                norm2 += sum.real() * sum.real();
            }
    double inv = 1.0 / std::sqrt(norm2);
    for (int t = 0; t < n1 * n2 * n3; ++t) outp[t] *= inv;
}

// ======================================================================
// Sparsity pattern of the real-basis w3j (structural nonzeros).
// ======================================================================

struct E3 { unsigned char i, j, k; };

constexpr E3 PAT_P0[1]  = {{0,0,0}};
constexpr E3 PAT_P1[3]  = {{0,0,0},{1,1,0},{2,2,0}};
constexpr E3 PAT_P2[5]  = {{0,0,0},{1,1,0},{2,2,0},{3,3,0},{4,4,0}};
constexpr E3 PAT_P3[3]  = {{0,0,0},{0,1,1},{0,2,2}};
constexpr E3 PAT_P4[3]  = {{0,0,0},{1,0,1},{2,0,2}};
constexpr E3 PAT_P5[11] = {{1,2,1},{1,3,2},{1,1,0},{2,2,2},{0,2,0},{2,3,1},
                           {0,1,1},{2,4,2},{0,0,2},{2,0,0},{0,4,0}};
constexpr E3 PAT_P6[11] = {{2,1,1},{2,2,2},{2,0,0},{3,1,2},{1,1,0},{3,2,1},
                           {1,0,1},{4,2,2},{0,0,2},{4,0,0},{0,2,0}};
constexpr E3 PAT_P7[5]  = {{0,0,0},{0,1,1},{0,2,2},{0,3,3},{0,4,4}};
constexpr E3 PAT_P8[11] = {{1,1,2},{1,2,3},{1,0,1},{2,1,3},{0,1,1},{2,2,2},
                           {0,0,2},{2,2,4},{0,0,4},{2,0,0},{0,2,0}};
constexpr E3 PAT_P9[5]  = {{0,0,0},{1,0,1},{2,0,2},{3,0,3},{4,0,4}};
constexpr E3 PAT_P10[25]= {{2,2,2},{2,3,3},{2,1,1},{2,4,4},{2,0,0},{3,2,3},
                           {1,2,1},{3,3,2},{1,1,2},{3,3,4},{1,1,4},{3,1,0},
                           {1,3,0},{3,4,3},{1,0,3},{3,0,1},{1,4,1},{4,2,4},
                           {0,2,0},{4,3,3},{0,1,3},{4,1,1},{0,3,1},{4,4,2},
                           {0,0,2}};

constexpr int OFF_P[11] = {0, 1, 4, 9, 12, 15, 26, 37, 42, 53, 58};

struct W3JArg { float c[83]; };

static W3JArg build_w3j_sparse() {
    struct PD { const E3* pat; int ne; int l1, l2, lo; double alpha; };
    const double a0 = std::sqrt(1.0/3072.0), a1 = std::sqrt(3.0/4096.0),
                 a2 = std::sqrt(5.0/4096.0);
    const PD pd[11] = {
        {PAT_P0, 1, 0,0,0, a0}, {PAT_P1, 3, 1,1,0, a0}, {PAT_P2, 5, 2,2,0, a0},
        {PAT_P3, 3, 0,1,1, a1}, {PAT_P4, 3, 1,0,1, a1}, {PAT_P5,11, 1,2,1, a1},
        {PAT_P6,11, 2,1,1, a1}, {PAT_P7, 5, 0,2,2, a2}, {PAT_P8,11, 1,1,2, a2},
        {PAT_P9, 5, 2,0,2, a2}, {PAT_P10,25,2,2,2, a2}
    };
    W3JArg arg;
    for (int p = 0; p < 11; ++p) {
        double dense[125];
        wigner3j_dense(pd[p].l1, pd[p].l2, pd[p].lo, dense);
        int n2 = 2*pd[p].l2+1, n3 = 2*pd[p].lo+1;
        for (int e = 0; e < pd[p].ne; ++e) {
            const E3& t = pd[p].pat[e];
            arg.c[OFF_P[p] + e] =
                (float)(dense[(t.i * n2 + t.j) * n3 + t.k] * pd[p].alpha);
        }
    }
    return arg;
}

// ======================================================================
// Device
// ======================================================================

typedef __attribute__((ext_vector_type(8))) short short8;
typedef __attribute__((ext_vector_type(4))) float f32x4;

__device__ __forceinline__ unsigned short f2bf_bits(float f) {
    __hip_bfloat16 h = __float2bfloat16(f);
    unsigned short u; __builtin_memcpy(&u, &h, 2); return u;
}

__device__ __forceinline__ unsigned pack2(float lo, float hi) {
    float2 f2; f2.x = lo; f2.y = hi;
    __hip_bfloat162 pk = __float22bfloat162_rn(f2);
    unsigned u; __builtin_memcpy(&u, &pk, 4); return u;
}

// One path: ca_e = c_e*a[i_e] once, then t0/t1 FMAs; pack + LDS store.
template<int NE, int A1, int A2, int D3, int SBASE, int SSTR>
__device__ __forceinline__ void do_path(const E3 (&pat)[NE],
                                        const float* __restrict__ cs,
                                        const float* a, const float* b0,
                                        const float* b1,
                                        unsigned* __restrict__ dst) {
    float ca[NE];
    #pragma unroll
    for (int e = 0; e < NE; ++e) ca[e] = cs[e] * a[A1 + pat[e].i];
    float t0[D3], t1[D3];
    #pragma unroll
    for (int k = 0; k < D3; ++k) { t0[k] = 0.0f; t1[k] = 0.0f; }
    #pragma unroll
    for (int e = 0; e < NE; ++e) {
        const int k = pat[e].k;
        t0[k] = fmaf(ca[e], b0[A2 + pat[e].j], t0[k]);
        t1[k] = fmaf(ca[e], b1[A2 + pat[e].j], t1[k]);
    }
    #pragma unroll
    for (int k = 0; k < D3; ++k)
        dst[(SBASE + k * SSTR) * 256] = pack2(t0[k], t1[k]);
}

__device__ __forceinline__ void build_all(const float* __restrict__ cs,
                                          const float* a, const float* b0,
                                          const float* b1,
                                          unsigned* __restrict__ dst) {
    do_path< 1,0,0,1, 0,1>(PAT_P0,  cs +  0, a, b0, b1, dst);
    do_path< 3,1,1,1, 1,1>(PAT_P1,  cs +  1, a, b0, b1, dst);
    do_path< 5,4,4,1, 2,1>(PAT_P2,  cs +  4, a, b0, b1, dst);
    do_path< 3,0,1,3, 3,4>(PAT_P3,  cs +  9, a, b0, b1, dst);
    do_path< 3,1,0,3, 4,4>(PAT_P4,  cs + 12, a, b0, b1, dst);
    do_path<11,1,4,3, 5,4>(PAT_P5,  cs + 15, a, b0, b1, dst);
    do_path<11,4,1,3, 6,4>(PAT_P6,  cs + 26, a, b0, b1, dst);
    do_path< 5,0,4,5,15,4>(PAT_P7,  cs + 37, a, b0, b1, dst);
    do_path<11,1,1,5,16,4>(PAT_P8,  cs + 42, a, b0, b1, dst);
    do_path< 5,4,0,5,17,4>(PAT_P9,  cs + 53, a, b0, b1, dst);
    do_path<25,4,4,5,18,4>(PAT_P10, cs + 58, a, b0, b1, dst);
}

__device__ __forceinline__ void load_a(const float* __restrict__ x1r, int u,
                                       float* a) {
    a[0] = x1r[u];
    #pragma unroll
    for (int i = 0; i < 3; ++i) a[1 + i] = x1r[32 + u * 3 + i];
    #pragma unroll
    for (int i = 0; i < 5; ++i) a[4 + i] = x1r[128 + u * 5 + i];
}

// B fragment: wsT[p][u][w][v] bf16; lane: n = l&15 -> w, k = (l>>4)*8+j -> v
template<bool USE_WST>
__device__ __forceinline__ short8 load_bfrag(const float* __restrict__ ws,
                                             const unsigned short* __restrict__ wsT,
                                             int p, int u, int w, int vbase) {
    if constexpr (USE_WST) {
        return *(const short8*)(wsT + (((size_t)(p*32+u)*32 + w)*32 + vbase));
    } else {
        short8 r;
        #pragma unroll
        for (int j = 0; j < 8; ++j) {
            float f = ws[((size_t)(p*32+u)*32 + (vbase+j))*32 + w];
            r[j] = (short)f2bf_bits(f);
        }
        return r;
    }
}

// ws prep: wsT[p][u][w][v] bf16 <- ws[p][u][v][w] fp32
__global__ void ws_prep(const float* __restrict__ ws,
                        unsigned short* __restrict__ wsT) {
    __shared__ float tile[32][33];
    const int pu = blockIdx.x, tid = threadIdx.x;
    const float4 f = ((const float4*)(ws + (size_t)pu * 1024))[tid];
    const int v = tid >> 3, w0 = (tid & 7) * 4;
    tile[v][w0+0] = f.x; tile[v][w0+1] = f.y; tile[v][w0+2] = f.z; tile[v][w0+3] = f.w;
    __syncthreads();
    const int w = tid >> 3, vB = (tid & 7) * 4;
    ushort4 o;
    o.x = f2bf_bits(tile[vB+0][w]); o.y = f2bf_bits(tile[vB+1][w]);
    o.z = f2bf_bits(tile[vB+2][w]); o.w = f2bf_bits(tile[vB+3][w]);
    *(ushort4*)(wsT + (size_t)pu * 1024 + tid * 4) = o;
}

// ======================================================================
// Main kernel. Block 256 = 16 z x 16 v-pairs (build) = 4 MFMA waves
// (kh: slot-group) x (nt: w-half). Grid = 8 u-groups x (B/16) z-tiles.
// K-loop order: barrier#1 -> ISSUE GLOBAL LOADS -> build (~640 cyc covers
// L2 latency) -> barrier#2 (vmcnt drain now free) -> MFMA. Loads issued
// before a barrier would be drained there with full latency exposed
// (compiler emits s_waitcnt vmcnt(0) before s_barrier).
// Epilogue: contention-free coalesced fp32 partial stores to d_ws:
//   part[ug][zt][comp(9)][zi(16)][w(32)]
// ======================================================================

__launch_bounds__(256, 4)
__global__ void tp_mfma(const float* __restrict__ x1,
                        const float* __restrict__ x2,
                        const unsigned short* __restrict__ wsT,
                        float* __restrict__ part, int ZT, W3JArg w3j) {
    __shared__ unsigned shT[35 * 256];  // T[s][z(16)][v-word(16)], swizzled

    const int tid = threadIdx.x;
    const int l = tid & 63, wv = tid >> 6, kh = wv & 1, nt = wv >> 1;
    const int zt = blockIdx.x & (ZT - 1);
    const int ug = blockIdx.x / ZT;
    const int z0 = zt * 16, u0 = ug * 4;
    const int tz = tid >> 4, vp = tid & 15, v0 = vp * 2;

    // ---- b0/b1 (x2 components for v0, v0+1) straight from global ----
    float b0[9], b1[9];
    {
        const float* xr = x2 + (size_t)(z0 + tz) * 288;
        float2 s0 = *(const float2*)(xr + v0);
        b0[0] = s0.x; b1[0] = s0.y;
        const float* p1 = xr + 32 + v0 * 3;
        float2 q0 = *(const float2*)(p1 + 0);
        float2 q1 = *(const float2*)(p1 + 2);
        float2 q2 = *(const float2*)(p1 + 4);
        b0[1] = q0.x; b0[2] = q0.y; b0[3] = q1.x;
        b1[1] = q1.y; b1[2] = q2.x; b1[3] = q2.y;
        const float* p2 = xr + 128 + v0 * 5;
        #pragma unroll
        for (int h = 0; h < 5; ++h) {
            float2 r = *(const float2*)(p2 + 2 * h);
            if (2 * h < 5) b0[4 + 2 * h] = r.x; else b1[4 + 2 * h - 5] = r.x;
            if (2 * h + 1 < 5) b0[5 + 2 * h] = r.y; else b1[4 + 2 * h - 4] = r.y;
        }
    }

    const float* x1r = x1 + (size_t)(z0 + tz) * 288;

    // swizzled LDS bases
    unsigned* dstT = shT + tz * 16 + (vp & 3) + ((((vp >> 2) + (tz >> 1)) & 3) << 2);
    const unsigned* tbase = shT + (l & 15) * 16 +
                            ((((l >> 4) + ((l & 15) >> 1)) & 3) << 2);

    const int w  = (l & 15) + nt * 16;   // N index (output mul w)
    const int vb = (l >> 4) * 8;         // K base (v)

    f32x4 acc[5];
    #pragma unroll
    for (int i = 0; i < 5; ++i) acc[i] = (f32x4)(0.0f);

    float a[2][9];
    load_a(x1r, u0, a[0]);

    for (int ui = 0; ui < 4; ++ui) {
        const int u = u0 + ui;
        const int cur = ui & 1;

        __syncthreads();   // prior MFMA reads of shT complete (lgkm only; quick)

        // ISSUE loads now: ~640 cyc of build ahead -> L2 latency fully hidden
        // before barrier#2's vmcnt(0) drain.
        short8 bf[7];
        if (kh == 0) {
            #pragma unroll
            for (int p = 0; p < 7; ++p) bf[p] = load_bfrag<true>(nullptr, wsT, p, u, w, vb);
        } else {
            #pragma unroll
            for (int p = 0; p < 4; ++p) bf[p] = load_bfrag<true>(nullptr, wsT, 7 + p, u, w, vb);
        }
        if (ui < 3) load_a(x1r, u + 1, a[cur ^ 1]);

        build_all(w3j.c, a[cur], b0, b1, dstT);
        __syncthreads();

        // ---- MFMA phase (wave-specialized; same-target slots chain) ----
        if (kh == 0) {
            #pragma unroll
            for (int m = 0; m < 3; ++m) {
                short8 af = *(const short8*)(tbase + m * 256);
                acc[0] = __builtin_amdgcn_mfma_f32_16x16x32_bf16(af, bf[m], acc[0], 0, 0, 0);
            }
            #pragma unroll
            for (int g = 0; g < 3; ++g)
                #pragma unroll
                for (int m = 0; m < 4; ++m) {
                    short8 af = *(const short8*)(tbase + (3 + g*4 + m) * 256);
                    acc[1+g] = __builtin_amdgcn_mfma_f32_16x16x32_bf16(af, bf[3+m], acc[1+g], 0, 0, 0);
                }
        } else {
            #pragma unroll
            for (int g = 0; g < 5; ++g)
                #pragma unroll
                for (int m = 0; m < 4; ++m) {
                    short8 af = *(const short8*)(tbase + (15 + g*4 + m) * 256);
                    acc[g] = __builtin_amdgcn_mfma_f32_16x16x32_bf16(af, bf[m], acc[g], 0, 0, 0);
                }
        }
    }

    // ---- epilogue: coalesced partial stores (no atomics, no contention) ----
    float* pb = part + ((size_t)(ug * ZT + zt) * 9) * 512;
    const int zi4 = (l >> 4) << 2;
    if (kh == 0) {
        #pragma unroll
        for (int r = 0; r < 4; ++r)
            pb[(zi4 + r) * 32 + w] = acc[0][r];
        #pragma unroll
        for (int k = 0; k < 3; ++k)
            #pragma unroll
            for (int r = 0; r < 4; ++r)
                pb[(1 + k) * 512 + (zi4 + r) * 32 + w] = acc[1 + k][r];
    } else {
        #pragma unroll
        for (int k = 0; k < 5; ++k)
            #pragma unroll
            for (int r = 0; r < 4; ++r)
                pb[(4 + k) * 512 + (zi4 + r) * 32 + w] = acc[k][r];
    }
}

// ======================================================================
// Reduce: out[z][col] = sum_ug part[ug][zt][comp][zi][w].
// ======================================================================

__global__ void reduce_out(const float* __restrict__ part,
                           float* __restrict__ out, int ZT) {
    const int bid = blockIdx.x;
    const int zt = bid / 9, comp = bid - zt * 9;
    const int tid = threadIdx.x;
    #pragma unroll
    for (int h = 0; h < 2; ++h) {
        const int e = tid + h * 256;          // 0..511
        const int zi = e >> 5, w = e & 31;
        float s = 0.0f;
        #pragma unroll
        for (int g = 0; g < 8; ++g)
            s += part[((size_t)(g * ZT + zt) * 9 + comp) * 512 + e];
        int col;
        if (comp == 0)      col = w;
        else if (comp < 4)  col = 32 + w * 3 + (comp - 1);
        else                col = 128 + w * 5 + (comp - 4);
        out[(size_t)(zt * 16 + zi) * 288 + col] = s;
    }
}

// ======================================================================
// Fallback (workspace too small): atomic epilogue, fp32 ws, zeroed out.
// ======================================================================

__launch_bounds__(256, 4)
__global__ void tp_mfma_atomic(const float* __restrict__ x1,
                               const float* __restrict__ x2,
                               const float* __restrict__ ws,
                               float* __restrict__ out, int ZT, W3JArg w3j) {
    __shared__ unsigned shT[35 * 256];
    const int tid = threadIdx.x;
    const int l = tid & 63, wv = tid >> 6, kh = wv & 1, nt = wv >> 1;
    const int zt = blockIdx.x & (ZT - 1);
    const int ug = blockIdx.x / ZT;
    const int z0 = zt * 16, u0 = ug * 4;
    const int tz = tid >> 4, vp = tid & 15, v0 = vp * 2;

    float b0[9], b1[9];
    {
        const float* xr = x2 + (size_t)(z0 + tz) * 288;
        float2 s0 = *(const float2*)(xr + v0);
        b0[0] = s0.x; b1[0] = s0.y;
        const float* p1 = xr + 32 + v0 * 3;
        float2 q0 = *(const float2*)(p1 + 0);
        float2 q1 = *(const float2*)(p1 + 2);
        float2 q2 = *(const float2*)(p1 + 4);
        b0[1] = q0.x; b0[2] = q0.y; b0[3] = q1.x;
        b1[1] = q1.y; b1[2] = q2.x; b1[3] = q2.y;
        const float* p2 = xr + 128 + v0 * 5;
        #pragma unroll
        for (int h = 0; h < 5; ++h) {
            float2 r = *(const float2*)(p2 + 2 * h);
            if (2 * h < 5) b0[4 + 2 * h] = r.x; else b1[4 + 2 * h - 5] = r.x;
            if (2 * h + 1 < 5) b0[5 + 2 * h] = r.y; else b1[4 + 2 * h - 4] = r.y;
        }
    }
    const float* x1r = x1 + (size_t)(z0 + tz) * 288;
    unsigned* dstT = shT + tz * 16 + (vp & 3) + ((((vp >> 2) + (tz >> 1)) & 3) << 2);
    const unsigned* tbase = shT + (l & 15) * 16 +
                            ((((l >> 4) + ((l & 15) >> 1)) & 3) << 2);
    const int w  = (l & 15) + nt * 16;
    const int vb = (l >> 4) * 8;

    f32x4 acc[5];
    #pragma unroll
    for (int i = 0; i < 5; ++i) acc[i] = (f32x4)(0.0f);
    float a[2][9];
    load_a(x1r, u0, a[0]);

    for (int ui = 0; ui < 4; ++ui) {
        const int u = u0 + ui;
        const int cur = ui & 1;
        __syncthreads();
        short8 bf[7];
        if (kh == 0) {
            #pragma unroll
            for (int p = 0; p < 7; ++p) bf[p] = load_bfrag<false>(ws, nullptr, p, u, w, vb);
        } else {
            #pragma unroll
            for (int p = 0; p < 4; ++p) bf[p] = load_bfrag<false>(ws, nullptr, 7 + p, u, w, vb);
        }
        if (ui < 3) load_a(x1r, u + 1, a[cur ^ 1]);
        build_all(w3j.c, a[cur], b0, b1, dstT);
        __syncthreads();
        if (kh == 0) {
            #pragma unroll
            for (int m = 0; m < 3; ++m) {
                short8 af = *(const short8*)(tbase + m * 256);
                acc[0] = __builtin_amdgcn_mfma_f32_16x16x32_bf16(af, bf[m], acc[0], 0, 0, 0);
            }
            #pragma unroll
            for (int g = 0; g < 3; ++g)
                #pragma unroll
                for (int m = 0; m < 4; ++m) {
                    short8 af = *(const short8*)(tbase + (3 + g*4 + m) * 256);
                    acc[1+g] = __builtin_amdgcn_mfma_f32_16x16x32_bf16(af, bf[3+m], acc[1+g], 0, 0, 0);
                }
        } else {
            #pragma unroll
            for (int g = 0; g < 5; ++g)
                #pragma unroll
                for (int m = 0; m < 4; ++m) {
                    short8 af = *(const short8*)(tbase + (15 + g*4 + m) * 256);
                    acc[g] = __builtin_amdgcn_mfma_f32_16x16x32_bf16(af, bf[m], acc[g], 0, 0, 0);
                }
        }
    }
    const int zr = z0 + ((l >> 4) << 2);
    if (kh == 0) {
        #pragma unroll
        for (int r = 0; r < 4; ++r)
            atomicAdd(&out[(size_t)(zr + r) * 288 + w], acc[0][r]);
        #pragma unroll
        for (int k = 0; k < 3; ++k)
            #pragma unroll
            for (int r = 0; r < 4; ++r)
                atomicAdd(&out[(size_t)(zr + r) * 288 + 32 + w*3 + k], acc[1+k][r]);
    } else {
        #pragma unroll
        for (int k = 0; k < 5; ++k)
            #pragma unroll
            for (int r = 0; r < 4; ++r)
                atomicAdd(&out[(size_t)(zr + r) * 288 + 128 + w*5 + k], acc[k][r]);
    }
}

// ======================================================================

extern "C" void kernel_launch(void* const* d_in, const int* in_sizes, int n_in,
                              void* d_out, int out_size, void* d_ws, size_t ws_size,
                              hipStream_t stream) {
    const float* x1 = (const float*)d_in[0];
    const float* x2 = (const float*)d_in[1];
    const float* ws = (const float*)d_in[2];
    float* out = (float*)d_out;

    static const W3JArg arg = build_w3j_sparse();

    const int B = in_sizes[0] / 288;          // 2048
    const int ZT = B / 16;                    // 128 z-tiles
    const int grid_main = 8 * ZT;             // 8 u-groups

    const size_t part_off_b = 786432;                          // 768 KB aligned
    const size_t part_bytes = (size_t)8 * ZT * 9 * 512 * 4;    // 18.9 MB

    if (ws_size >= part_off_b + part_bytes) {
        unsigned short* wsT = (unsigned short*)d_ws;
        float* part = (float*)((char*)d_ws + part_off_b);
        ws_prep<<<dim3(11 * 32), dim3(256), 0, stream>>>(ws, wsT);
        tp_mfma<<<dim3(grid_main), dim3(256), 0, stream>>>(x1, x2, wsT, part, ZT, arg);
        reduce_out<<<dim3(ZT * 9), dim3(256), 0, stream>>>(part, out, ZT);
    } else {
        hipMemsetAsync(out, 0, (size_t)out_size * sizeof(float), stream);
        tp_mfma_atomic<<<dim3(grid_main), dim3(256), 0, stream>>>(x1, x2, ws, out, ZT, arg);
    }
}